// Round 8
// baseline (49.343 us; speedup 1.0000x reference)
//
#include <hip/hip_runtime.h>
#include <math.h>
#include <stdint.h>

#define HH 2048
#define WW 2048

typedef float f2v __attribute__((ext_vector_type(2)));
typedef float f4  __attribute__((ext_vector_type(4)));

// Gaussian sigma=2, 5 taps, normalized
#define GW0 0.15246914402033867f
#define GW1 0.22184129554377693f
#define GW2 0.25137912086578894f

// Composed separable 9-tap filters (double-derived):
// P = [1,4,6,4,1]/16 * g  (symmetric), Q = [1,0,-2,0,1]/4 * g (symmetric),
// R = [-1,-2,0,2,1]/8 * g (antisymmetric, positive side below)
#define CP0 0.22424646109910165f
#define CP1 0.19801763302193431f
#define CP2 0.12834744794768304f
#define CP3 0.05198236697657073f
#define CP4 0.009529321501271167f
#define CQ0 -0.049454988422725135f
#define CQ1 -0.055460323885944233f
#define CQ2 -0.0133897917937221f
#define CQ3 0.055460323885944233f
#define CQ4 0.038117286005084667f
#define CR1 0.052457281154334684f
#define CR2 0.08688271399416785f
#define CR3 0.065847447948056784f
#define CR4 0.019058643002542333f

#define NWI 4590            // interior waves: 9 x-strips * 510 row groups
#define NWB 1036            // border waves: 16 tb + 1020 lr
#define NACC (NWI + NWB)

struct E8 { float v[8]; };

// ============================ interior kernel ============================
__global__ __launch_bounds__(256) void steal_interior(const float* __restrict__ pred,
                                                      const float* __restrict__ lab,
                                                      float* __restrict__ acc) {
    const int lane = threadIdx.x & 63;
    const int wid  = (blockIdx.x << 2) + (threadIdx.x >> 6);
    if (wid >= NWI) return;
    const int w  = wid % 9;             // x-strip 0..8
    const int rg = wid / 9;             // row group 0..509
    const int y0 = 4 + rg * 4;          // output rows y0..y0+3 (4..2043)
    const int cb  = w * 248 + lane * 4; // own col base (valid lanes 1..62)
    const int cbc = min(cb, 2044);      // clamped load base (w=8 high lanes)
    const bool lvalid = (lane >= 1) && (lane <= 62);

    const float T1f = 0.41421356237309503f;   // tan(pi/8)
    const float T3f = 2.41421356237309510f;   // tan(3pi/8)

    float lsum = 0.f;

    auto primeE = [&](int ry, f4& peSave) -> E8 {
        f4 pe = *(const f4*)(pred + (size_t)ry * WW + cbc);
        f4 ex;
        ex.x = __expf(pe.x * 10.f); ex.y = __expf(pe.y * 10.f);
        ex.z = __expf(pe.z * 10.f); ex.w = __expf(pe.w * 10.f);
        E8 r;
        r.v[2] = ex.x; r.v[3] = ex.y; r.v[4] = ex.z; r.v[5] = ex.w;
        r.v[0] = __shfl_up(ex.z, 1);  r.v[1] = __shfl_up(ex.w, 1);
        r.v[6] = __shfl_down(ex.x, 1); r.v[7] = __shfl_down(ex.y, 1);
        peSave = pe;
        return r;
    };

    auto step = [&](int y, const E8& eA, const E8& eB, const E8& eC, const E8& eD,
                    E8& eN, const f4& pcY, f4& peOut) {
        const float* lp = lab + (size_t)(y - 4) * WW + cbc;
        f4 l0 = *(const f4*)(lp);
        f4 l1 = *(const f4*)(lp + WW);
        f4 l2 = *(const f4*)(lp + 2 * WW);
        f4 l3 = *(const f4*)(lp + 3 * WW);
        f4 l4 = *(const f4*)(lp + 4 * WW);
        f4 l5 = *(const f4*)(lp + 5 * WW);
        f4 l6 = *(const f4*)(lp + 6 * WW);
        f4 l7 = *(const f4*)(lp + 7 * WW);
        f4 l8 = *(const f4*)(lp + 8 * WW);

        f4 vP = CP0 * l4 + CP1 * (l3 + l5) + CP2 * (l2 + l6) + CP3 * (l1 + l7) + CP4 * (l0 + l8);
        f4 vQ = CQ0 * l4 + CQ1 * (l3 + l5) + CQ2 * (l2 + l6) + CQ3 * (l1 + l7) + CQ4 * (l0 + l8);
        f4 vR = CR1 * (l5 - l3) + CR2 * (l6 - l2) + CR3 * (l7 - l1) + CR4 * (l8 - l0);

        float vp[12], vq[12], vr[12];
        vp[0] = __shfl_up(vP.x, 1); vp[1] = __shfl_up(vP.y, 1);
        vp[2] = __shfl_up(vP.z, 1); vp[3] = __shfl_up(vP.w, 1);
        vp[4] = vP.x; vp[5] = vP.y; vp[6] = vP.z; vp[7] = vP.w;
        vp[8] = __shfl_down(vP.x, 1); vp[9] = __shfl_down(vP.y, 1);
        vp[10] = __shfl_down(vP.z, 1); vp[11] = __shfl_down(vP.w, 1);
        vq[0] = __shfl_up(vQ.x, 1); vq[1] = __shfl_up(vQ.y, 1);
        vq[2] = __shfl_up(vQ.z, 1); vq[3] = __shfl_up(vQ.w, 1);
        vq[4] = vQ.x; vq[5] = vQ.y; vq[6] = vQ.z; vq[7] = vQ.w;
        vq[8] = __shfl_down(vQ.x, 1); vq[9] = __shfl_down(vQ.y, 1);
        vq[10] = __shfl_down(vQ.z, 1); vq[11] = __shfl_down(vQ.w, 1);
        vr[0] = __shfl_up(vR.x, 1); vr[1] = __shfl_up(vR.y, 1);
        vr[2] = __shfl_up(vR.z, 1); vr[3] = __shfl_up(vR.w, 1);
        vr[4] = vR.x; vr[5] = vR.y; vr[6] = vR.z; vr[7] = vR.w;
        vr[8] = __shfl_down(vR.x, 1); vr[9] = __shfl_down(vR.y, 1);
        vr[10] = __shfl_down(vR.z, 1); vr[11] = __shfl_down(vR.w, 1);

        // e row y+2 (rows y+2 in [6,2045] -> always real here)
        f4 pe = *(const f4*)(pred + (size_t)(y + 2) * WW + cbc);
        f4 ex;
        ex.x = __expf(pe.x * 10.f); ex.y = __expf(pe.y * 10.f);
        ex.z = __expf(pe.z * 10.f); ex.w = __expf(pe.w * 10.f);
        eN.v[2] = ex.x; eN.v[3] = ex.y; eN.v[4] = ex.z; eN.v[5] = ex.w;
        eN.v[0] = __shfl_up(ex.z, 1);  eN.v[1] = __shfl_up(ex.w, 1);
        eN.v[6] = __shfl_down(ex.x, 1); eN.v[7] = __shfl_down(ex.y, 1);
        peOut = pe;

        float pcv[4] = {pcY.x, pcY.y, pcY.z, pcY.w};
        #pragma unroll
        for (int k = 0; k < 4; ++k) {
            float gxx = CQ0 * vp[k + 4] + CQ1 * (vp[k + 3] + vp[k + 5]) +
                        CQ2 * (vp[k + 2] + vp[k + 6]) + CQ3 * (vp[k + 1] + vp[k + 7]) +
                        CQ4 * (vp[k] + vp[k + 8]);
            float gyy = CP0 * vq[k + 4] + CP1 * (vq[k + 3] + vq[k + 5]) +
                        CP2 * (vq[k + 2] + vq[k + 6]) + CP3 * (vq[k + 1] + vq[k + 7]) +
                        CP4 * (vq[k] + vq[k + 8]);
            float gxy = CR1 * (vr[k + 5] - vr[k + 3]) + CR2 * (vr[k + 6] - vr[k + 2]) +
                        CR3 * (vr[k + 7] - vr[k + 1]) + CR4 * (vr[k + 8] - vr[k]);

            float sg = -(gxy + 1e-6f);
            float sgn = (sg > 0.f) ? 1.f : ((sg < 0.f) ? -1.f : 0.f);
            float rt = gyy * sgn * __builtin_amdgcn_rcpf(gxx + 1e-6f);

            float hs  = eC.v[k] + eC.v[k+1] + eC.v[k+2] + eC.v[k+3] + eC.v[k+4];
            float vs  = eA.v[k+2] + eB.v[k+2] + eC.v[k+2] + eD.v[k+2] + eN.v[k+2];
            float dls = eA.v[k]   + eB.v[k+1] + eC.v[k+2] + eD.v[k+3] + eN.v[k+4];
            float dcs = eA.v[k+4] + eB.v[k+3] + eC.v[k+2] + eD.v[k+1] + eN.v[k];

            bool isH = (rt >= -T1f) && (rt < T1f);
            bool isL = (rt >=  T1f) && (rt < T3f);
            bool isC = (rt >= -T3f) && (rt < -T1f);
            bool has = isH || isL || isC || (rt >= T3f) || (rt < -T3f);  // false only NaN
            float resp = isH ? hs : (isL ? dls : (isC ? dcs : vs));
            float lv = pcv[k] * 10.f - __logf(resp + 1e-6f);
            bool keep = has && lvalid && (cb + k <= 2043);
            lsum += keep ? lv : 0.f;
        }
    };

    // prime e ring rows y0-2..y0+1 and pc for rows y0, y0+1
    f4 dmy0, dmy1, pca, pcb;
    E8 e0 = primeE(y0 - 2, dmy0);
    E8 e1 = primeE(y0 - 1, dmy1);
    E8 e2 = primeE(y0 + 0, pca);
    E8 e3 = primeE(y0 + 1, pcb);

    E8 g0, g1, g2, g3;
    f4 pcc, pcd, pce, pcf;
    step(y0 + 0, e0, e1, e2, e3, g0, pca, pcc);
    step(y0 + 1, e1, e2, e3, g0, g1, pcb, pcd);
    step(y0 + 2, e2, e3, g0, g1, g2, pcc, pce);
    step(y0 + 3, e3, g0, g1, g2, g3, pcd, pcf);

    #pragma unroll
    for (int off = 32; off; off >>= 1) lsum += __shfl_down(lsum, off, 64);
    if (lane == 0) acc[wid] = lsum;
}

// ============================ border kernel (R4 staged, proven) ============================
struct R8 { float v[8]; };
struct R6 { float v[6]; };
struct Raw { f4 a, b, c; };

__device__ __forceinline__ int reflect_row(int vr) {
    return vr < 0 ? -vr : (vr >= HH ? 2 * HH - 2 - vr : vr);
}

__device__ __forceinline__ Raw load_row3(const float* __restrict__ p, int r, int xb) {
    const float* row = p + (size_t)r * WW;
    Raw o;
    o.a = *(const f4*)(row + max(xb - 4, 0));
    o.b = *(const f4*)(row + xb);
    o.c = *(const f4*)(row + min(xb + 4, WW - 4));
    return o;
}

__device__ __forceinline__ R8 make_h(const Raw& R, bool edgew, bool le, bool re) {
    float w[12] = {R.a.x, R.a.y, R.a.z, R.a.w, R.b.x, R.b.y, R.b.z, R.b.w,
                   R.c.x, R.c.y, R.c.z, R.c.w};
    if (edgew) {
        if (le) { w[0] = R.c.x; w[1] = R.b.w; w[2] = R.b.z; w[3] = R.b.y; }
        if (re) { w[8] = R.b.z; w[9] = R.b.y; w[10] = R.b.x; w[11] = R.a.w; }
    }
    R8 h;
    #pragma unroll
    for (int j = 0; j < 8; ++j)
        h.v[j] = GW0 * (w[j] + w[j + 4]) + GW1 * (w[j + 1] + w[j + 3]) + GW2 * w[j + 2];
    return h;
}

__device__ __forceinline__ R8 vg(const R8& a, const R8& b, const R8& c, const R8& d, const R8& e_,
                                 bool edgew, bool le, bool re) {
    R8 o;
    #pragma unroll
    for (int j = 0; j < 8; ++j)
        o.v[j] = GW0 * (a.v[j] + e_.v[j]) + GW1 * (b.v[j] + d.v[j]) + GW2 * c.v[j];
    if (edgew) {
        if (le) { o.v[0] = o.v[2]; o.v[1] = o.v[2]; }
        if (re) { o.v[6] = o.v[5]; o.v[7] = o.v[5]; }
    }
    return o;
}

__device__ __forceinline__ void sobel(const R8& u, const R8& m, const R8& d, R6& ox, R6& oy,
                                      bool edgew, bool le, bool re) {
    #pragma unroll
    for (int j = 0; j < 6; ++j) {
        ox.v[j] = ((u.v[j+2] - u.v[j]) + 2.f*(m.v[j+2] - m.v[j]) + (d.v[j+2] - d.v[j])) * 0.125f;
        oy.v[j] = ((d.v[j] - u.v[j]) + 2.f*(d.v[j+1] - u.v[j+1]) + (d.v[j+2] - u.v[j+2])) * 0.125f;
    }
    if (edgew) {
        if (le) { ox.v[0] = ox.v[1]; oy.v[0] = oy.v[1]; }
        if (re) { ox.v[5] = ox.v[4]; oy.v[5] = oy.v[4]; }
    }
}

__device__ __forceinline__ R8 erow(const float* __restrict__ pred, int ry, int xb,
                                   bool edgew, bool le, bool re) {
    R8 o;
    if (ry < 0 || ry >= HH) {
        #pragma unroll
        for (int j = 0; j < 8; ++j) o.v[j] = 0.f;
        return o;
    }
    const float* row = pred + (size_t)ry * WW;
    f4 A = *(const f4*)(row + max(xb - 4, 0));
    f4 B = *(const f4*)(row + xb);
    f4 C = *(const f4*)(row + min(xb + 4, WW - 4));
    float w[8] = {A.z, A.w, B.x, B.y, B.z, B.w, C.x, C.y};
    #pragma unroll
    for (int j = 0; j < 8; ++j) o.v[j] = __expf(w[j] * 10.f);
    if (edgew) {
        if (le) { o.v[0] = 0.f; o.v[1] = 0.f; }
        if (re) { o.v[6] = 0.f; o.v[7] = 0.f; }
    }
    return o;
}

__global__ __launch_bounds__(256) void steal_border(const float* __restrict__ pred,
                                                    const float* __restrict__ lab,
                                                    float* __restrict__ acc) {
    const int lane = threadIdx.x & 63;
    const int b = (blockIdx.x << 2) + (threadIdx.x >> 6);
    if (b >= NWB) return;
    int sx, y0, mm;   // mm: 0=all valid, 1=left (lane0), 2=right (lane63)
    if (b < 16) { sx = b & 7; y0 = (b >> 3) ? 2044 : 0; mm = 0; }
    else { int j = b - 16; int side = j & 1; int r = j >> 1; y0 = 4 + 4 * r; sx = side ? 7 : 0; mm = 1 + side; }
    const int xb = sx * 256 + lane * 4;
    const bool edgew = (sx == 0) || (sx == 7);
    const bool le = (sx == 0) && (lane == 0);
    const bool re = (sx == 7) && (lane == 63);
    const bool lvalid = (mm == 0) || (mm == 1 && lane == 0) || (mm == 2 && lane == 63);

    const float T1f = 0.41421356237309503f;
    const float T3f = 2.41421356237309510f;

    R8 H0, H1, H2, H3, b0, b1;
    R6 gx0, gy0, gx1, gy1;
    {
        Raw r0 = load_row3(lab, reflect_row(y0 - 4), xb);
        Raw r1 = load_row3(lab, reflect_row(y0 - 3), xb);
        Raw r2 = load_row3(lab, reflect_row(y0 - 2), xb);
        Raw r3 = load_row3(lab, reflect_row(y0 - 1), xb);
        R8 A0 = make_h(r0, edgew, le, re);
        R8 A1 = make_h(r1, edgew, le, re);
        R8 A2 = make_h(r2, edgew, le, re);
        R8 A3 = make_h(r3, edgew, le, re);
        Raw r4 = load_row3(lab, y0 + 0, xb);
        Raw r5 = load_row3(lab, y0 + 1, xb);
        Raw r6 = load_row3(lab, y0 + 2, xb);
        Raw r7 = load_row3(lab, y0 + 3, xb);
        H0 = make_h(r4, edgew, le, re);
        H1 = make_h(r5, edgew, le, re);
        H2 = make_h(r6, edgew, le, re);
        H3 = make_h(r7, edgew, le, re);
        R8 bm2 = vg(A0, A1, A2, A3, H0, edgew, le, re);
        R8 bm1 = vg(A1, A2, A3, H0, H1, edgew, le, re);
        b0 = vg(A2, A3, H0, H1, H2, edgew, le, re);
        b1 = vg(A3, H0, H1, H2, H3, edgew, le, re);
        if (y0 > 0) {
            sobel(bm2, bm1, b0, gx0, gy0, edgew, le, re);
            sobel(bm1, b0,  b1, gx1, gy1, edgew, le, re);
        } else {
            sobel(b0, b0, b1, gx1, gy1, edgew, le, re);
            gx0 = gx1; gy0 = gy1;
        }
    }

    R8 e0 = erow(pred, y0 - 2, xb, edgew, le, re);
    R8 e1 = erow(pred, y0 - 1, xb, edgew, le, re);
    R8 e2 = erow(pred, y0 + 0, xb, edgew, le, re);
    R8 e3 = erow(pred, y0 + 1, xb, edgew, le, re);

    float lsum = 0.f;

    #pragma unroll
    for (int i = 0; i < 4; ++i) {
        const int y = y0 + i;

        R8 bn;
        if (y + 2 < HH) {
            R8 hn = make_h(load_row3(lab, reflect_row(y + 4), xb), edgew, le, re);
            bn = vg(H0, H1, H2, H3, hn, edgew, le, re);
            H0 = H1; H1 = H2; H2 = H3; H3 = hn;
        } else bn = b1;

        R6 gxn, gyn;
        if (y + 1 < HH) sobel(b0, b1, bn, gxn, gyn, edgew, le, re);
        else { gxn = gx1; gyn = gy1; }

        R8 en = erow(pred, y + 2, xb, edgew, le, re);

        f4 pc4 = *(const f4*)(pred + (size_t)y * WW + xb);
        float pcv[4] = {pc4.x, pc4.y, pc4.z, pc4.w};

        #pragma unroll
        for (int k = 0; k < 4; ++k) {
            float gxx = ((gx0.v[k+2]-gx0.v[k]) + 2.f*(gx1.v[k+2]-gx1.v[k]) +
                         (gxn.v[k+2]-gxn.v[k])) * 0.125f;
            float gxy = ((gy0.v[k+2]-gy0.v[k]) + 2.f*(gy1.v[k+2]-gy1.v[k]) +
                         (gyn.v[k+2]-gyn.v[k])) * 0.125f;
            float gyy = ((gyn.v[k]-gy0.v[k]) + 2.f*(gyn.v[k+1]-gy0.v[k+1]) +
                         (gyn.v[k+2]-gy0.v[k+2])) * 0.125f;
            float sg = -(gxy + 1e-6f);
            float sgn = (sg > 0.f) ? 1.f : ((sg < 0.f) ? -1.f : 0.f);
            float rt = gyy * sgn * __builtin_amdgcn_rcpf(gxx + 1e-6f);

            float hs  = e2.v[k] + e2.v[k+1] + e2.v[k+2] + e2.v[k+3] + e2.v[k+4];
            float vs  = e0.v[k+2] + e1.v[k+2] + e2.v[k+2] + e3.v[k+2] + en.v[k+2];
            float dls = e0.v[k]   + e1.v[k+1] + e2.v[k+2] + e3.v[k+3] + en.v[k+4];
            float dcs = e0.v[k+4] + e1.v[k+3] + e2.v[k+2] + e3.v[k+1] + en.v[k];

            bool isH = (rt >= -T1f) && (rt < T1f);
            bool isL = (rt >=  T1f) && (rt < T3f);
            bool isC = (rt >= -T3f) && (rt < -T1f);
            bool has = isH || isL || isC || (rt >= T3f) || (rt < -T3f);
            float resp = isH ? hs : (isL ? dls : (isC ? dcs : vs));
            float lv = pcv[k] * 10.f - __logf(resp + 1e-6f);
            lsum += (lvalid && has) ? lv : 0.f;
        }

        b0 = b1; b1 = bn;
        gx0 = gx1; gx1 = gxn; gy0 = gy1; gy1 = gyn;
        e0 = e1; e1 = e2; e2 = e3; e3 = en;
    }

    #pragma unroll
    for (int off = 32; off; off >>= 1) lsum += __shfl_down(lsum, off, 64);
    if (lane == 0) acc[NWI + b] = lsum;
}

__global__ __launch_bounds__(256) void steal_finalize(const float* __restrict__ acc,
                                                      float* __restrict__ out, int n) {
    __shared__ double sd[256];
    double a = 0.0;
    int n4 = n >> 2;
    for (int i = threadIdx.x; i < n4; i += 256) {
        f4 v = *(const f4*)(acc + i * 4);
        a += (double)v.x + (double)v.y + (double)v.z + (double)v.w;
    }
    for (int i = (n4 << 2) + threadIdx.x; i < n; i += 256) a += (double)acc[i];
    sd[threadIdx.x] = a;
    __syncthreads();
    for (int s = 128; s > 0; s >>= 1) {
        if (threadIdx.x < s) sd[threadIdx.x] += sd[threadIdx.x + s];
        __syncthreads();
    }
    if (threadIdx.x == 0) out[0] = (float)(-sd[0] / 4194304.0);
}

extern "C" void kernel_launch(void* const* d_in, const int* in_sizes, int n_in,
                              void* d_out, int out_size, void* d_ws, size_t ws_size,
                              hipStream_t stream) {
    const float* pred = (const float*)d_in[0];   // (1,1,2048,2048) f32
    const float* lab  = (const float*)d_in[1];   // (1,2048,2048) f32
    float* out = (float*)d_out;                  // scalar f32
    float* ws  = (float*)d_ws;

    const int blkI = (NWI + 3) / 4;   // 1148
    const int blkB = (NWB + 3) / 4;   // 259

    steal_border<<<blkB, 256, 0, stream>>>(pred, lab, ws);
    steal_interior<<<blkI, 256, 0, stream>>>(pred, lab, ws);
    steal_finalize<<<1, 256, 0, stream>>>(ws, out, NACC);
}